// Round 8
// baseline (397.132 us; speedup 1.0000x reference)
//
#include <hip/hip_runtime.h>
#include <hip/hip_bf16.h>
#include <math.h>

#define NN 262144
#define NCC 65536

typedef __bf16 bf16x8 __attribute__((ext_vector_type(8)));
typedef __bf16 bf16x4 __attribute__((ext_vector_type(4)));
typedef float f32x4 __attribute__((ext_vector_type(4)));

// ---------- setup: blocks 0..47 precompute Mt; blocks 48..175 zero flags ----------
__global__ __launch_bounds__(256) void k_setup(const float* __restrict__ w_orig,
                                               const float* __restrict__ w_prop,
                                               const float* __restrict__ w_ctx,
                                               const float* __restrict__ W_fuse,
                                               __bf16* __restrict__ Mt,
                                               unsigned char* __restrict__ flags) {
    __shared__ float Wl[64 * 65];
    __shared__ float wl[64 * 65];
    int b = blockIdx.x;
    int t = threadIdx.x;
    if (b >= 48) {   // zero 2*NN flag bytes: 128 blocks * 256 threads * 16B
        ((uint4*)flags)[(b - 48) * 256 + t] = make_uint4(0u, 0u, 0u, 0u);
        return;
    }
    int seg = b >> 4, rem = b & 15;
    int ot = rem >> 2, mt = rem & 3;
    const float* wseg = seg == 0 ? w_orig : (seg == 1 ? w_prop : w_ctx);
    int to = (t & 15) * 4, tm = (t >> 4) * 4;
    float acc[4][4] = {};
    for (int kc = 0; kc < 4; ++kc) {
        __syncthreads();
        for (int i = 0; i < 16; ++i) {
            int f = i * 256 + t;
            int row = f >> 6, col = f & 63;
            Wl[row * 65 + col] = W_fuse[(size_t)(ot * 64 + row) * 768 + seg * 256 + kc * 64 + col];
            wl[row * 65 + col] = wseg[(size_t)(mt * 64 + row) * 256 + kc * 64 + col];
        }
        __syncthreads();
        for (int k = 0; k < 64; ++k) {
            float wo[4], wm2[4];
#pragma unroll
            for (int i = 0; i < 4; ++i) wo[i] = Wl[(to + i) * 65 + k];
#pragma unroll
            for (int j = 0; j < 4; ++j) wm2[j] = wl[(tm + j) * 65 + k];
#pragma unroll
            for (int i = 0; i < 4; ++i)
#pragma unroll
                for (int j = 0; j < 4; ++j) acc[i][j] += wo[i] * wm2[j];
        }
    }
    for (int i = 0; i < 4; ++i)
        for (int j = 0; j < 4; ++j) {
            int o = ot * 64 + to + i;
            int g = seg * 256 + mt * 64 + tm + j;
            Mt[(size_t)o * 768 + g] = (__bf16)acc[i][j];
        }
}

__global__ void k_setflags(const int* __restrict__ idxp, const int* __restrict__ idxc,
                           unsigned char* fp, unsigned char* fc) {
    int j = blockIdx.x * blockDim.x + threadIdx.x;
    if (j < NCC) { fp[idxp[j]] = 1; fc[idxc[j]] = 1; }
}

#define MFMA __builtin_amdgcn_mfma_f32_16x16x32_bf16

// ---------- unified block: gemm j-tile 32 + copy slabs 2x128 rows, fine-grained interleave ----------
__global__ __launch_bounds__(256, 4) void k_main(const float* __restrict__ hp,
                                                 const float* __restrict__ hc,
                                                 const float* __restrict__ horig,
                                                 const __bf16* __restrict__ Mt,
                                                 const float* __restrict__ bfuse,
                                                 const float* __restrict__ bias,
                                                 const int* __restrict__ idxp,
                                                 const int* __restrict__ idxc,
                                                 const unsigned char* __restrict__ fp,
                                                 const unsigned char* __restrict__ fc,
                                                 float* __restrict__ out0,
                                                 float* __restrict__ out1) {
    __shared__ char smem[16384];     // A-seg tile: 32 rows x 256 k bf16 (swizzled); reused as epilogue scratch
    int t = threadIdx.x;
    int bid = blockIdx.x;
    int lane = t & 63, wid = t >> 6;
    int l15 = lane & 15, lq = lane >> 4;
    int jbase = bid * 32;

    // A staging assignment: 8 threads per row, each owns a 128B (32-f32) slice
    int ar = t >> 3, asl = t & 7;
    int jr = jbase + ar;
    const float* arow0 = horig + (size_t)jr * 256;
    const float* arow1 = hp + (size_t)idxp[jr] * 256;
    const float* arow2 = hc + (size_t)idxc[jr] * 256;

    // B fragment base pointers (wave wid owns cols [wid*64, wid*64+64))
    const __bf16* bp[4];
#pragma unroll
    for (int ni = 0; ni < 4; ++ni)
        bp[ni] = Mt + (size_t)(wid * 64 + ni * 16 + l15) * 768 + lq * 8;

    f32x4 acc[2][4] = {};
    bf16x8 bA[4], bB[4];
#pragma unroll
    for (int ni = 0; ni < 4; ++ni) bA[ni] = *(const bf16x8*)(bp[ni]);   // cg=0, ks=0

    int copy_done = 0;

#pragma unroll
    for (int seg = 0; seg < 3; ++seg) {
        const float* src = seg == 0 ? arow0 : (seg == 1 ? arow1 : arow2);
        __syncthreads();   // previous seg's A reads complete
#pragma unroll
        for (int i = 0; i < 8; ++i) {
            f32x4 v = *(const f32x4*)(src + i * 32 + asl * 4);
            bf16x4 w;
            w[0] = (__bf16)v[0]; w[1] = (__bf16)v[1]; w[2] = (__bf16)v[2]; w[3] = (__bf16)v[3];
            int off = ar * 512 + ((i * 64 + asl * 8) ^ ((ar & 7) << 4));
            *(bf16x4*)(smem + off) = w;
        }
        __syncthreads();
#pragma unroll
        for (int c = 0; c < 4; ++c) {
            int cg = seg * 4 + c;
            // issue ks=1 B loads (covered by ks=0 MFMAs)
#pragma unroll
            for (int ni = 0; ni < 4; ++ni) bB[ni] = *(const bf16x8*)(bp[ni] + cg * 64 + 32);
            // A frags ks=0
            bf16x8 af0[2];
#pragma unroll
            for (int mi = 0; mi < 2; ++mi) {
                int row = mi * 16 + l15;
                int s = c * 8 + lq;
                af0[mi] = *(const bf16x8*)(smem + row * 512 + ((s ^ (row & 7)) << 4));
            }
#pragma unroll
            for (int mi = 0; mi < 2; ++mi)
#pragma unroll
                for (int ni = 0; ni < 4; ++ni)
                    acc[mi][ni] = MFMA(af0[mi], bA[ni], acc[mi][ni], 0, 0, 0);
            // prefetch next chunk's ks=0 B loads (covered by ks=1 MFMAs)
            if (cg < 11) {
#pragma unroll
                for (int ni = 0; ni < 4; ++ni) bA[ni] = *(const bf16x8*)(bp[ni] + (cg + 1) * 64);
            }
            // A frags ks=1
            bf16x8 af1[2];
#pragma unroll
            for (int mi = 0; mi < 2; ++mi) {
                int row = mi * 16 + l15;
                int s = c * 8 + 4 + lq;
                af1[mi] = *(const bf16x8*)(smem + row * 512 + ((s ^ (row & 7)) << 4));
            }
#pragma unroll
            for (int mi = 0; mi < 2; ++mi)
#pragma unroll
                for (int ni = 0; ni < 4; ++ni)
                    acc[mi][ni] = MFMA(af1[mi], bB[ni], acc[mi][ni], 0, 0, 0);

            // ---- interleaved copy quota: 16 steps spread over 12 chunks ----
            int tgt = ((cg + 1) * 16) / 12;
            for (; copy_done < tgt; ++copy_done) {
                int s = copy_done;
                int tbl = s >= 8;
                int r = (bid << 7) + (s & 7) * 16 + (t >> 4);      // 16 rows/step, 16 thr/row
                const unsigned char* F = tbl ? fc : fp;
                const float* S = tbl ? hc : hp;
                float* D = tbl ? out1 : out0;
                unsigned char f = F[r];
                // flagged rows: redirect read to slab-first row (cache-hot) -> loads unconditional
                const float* sp = S + (size_t)(f ? (bid << 7) : r) * 256 + (t & 15) * 16;
                f32x4 v0 = *(const f32x4*)(sp);
                f32x4 v1 = *(const f32x4*)(sp + 4);
                f32x4 v2 = *(const f32x4*)(sp + 8);
                f32x4 v3 = *(const f32x4*)(sp + 12);
                if (!f) {
                    float* dp = D + (size_t)r * 256 + (t & 15) * 16;
                    *(f32x4*)(dp) = v0;
                    *(f32x4*)(dp + 4) = v1;
                    *(f32x4*)(dp + 8) = v2;
                    *(f32x4*)(dp + 12) = v3;
                }
            }
        }
    }

    // ---- epilogue: per-wave LDS transpose (reuse A region) -> f32x4 contiguous scattered stores ----
    float bfv[4], biv[4];
#pragma unroll
    for (int ni = 0; ni < 4; ++ni) {
        int o = wid * 64 + ni * 16 + l15;
        bfv[ni] = bfuse[o];
        biv[ni] = bias[o];
    }
    __syncthreads();   // all A reads done; safe to reuse smem as scratch
    float* scr = (float*)(smem + wid * 4096);   // per-wave 16x64 f32
#pragma unroll
    for (int mi = 0; mi < 2; ++mi) {
#pragma unroll
        for (int ni = 0; ni < 4; ++ni)
#pragma unroll
            for (int rr = 0; rr < 4; ++rr) {
                float v = tanhf(acc[mi][ni][rr] + bfv[ni]) + biv[ni];
                scr[(lq * 4 + rr) * 64 + ni * 16 + l15] = v;
            }
#pragma unroll
        for (int rnd = 0; rnd < 4; ++rnd) {
            int rr2 = rnd * 4 + lq;
            int j = jbase + mi * 16 + rr2;
            int gp = idxp[j], gc = idxc[j];
            f32x4 v = *(const f32x4*)&scr[rr2 * 64 + l15 * 4];
            *(f32x4*)(out0 + (size_t)gp * 256 + wid * 64 + l15 * 4) = v;
            *(f32x4*)(out1 + (size_t)gc * 256 + wid * 64 + l15 * 4) = v;
        }
    }
}

extern "C" void kernel_launch(void* const* d_in, const int* in_sizes, int n_in,
                              void* d_out, int out_size, void* d_ws, size_t ws_size,
                              hipStream_t stream) {
    const float* hp     = (const float*)d_in[0];
    const float* hc     = (const float*)d_in[1];
    const float* horig  = (const float*)d_in[2];
    const float* w_orig = (const float*)d_in[3];
    const float* w_prop = (const float*)d_in[4];
    const float* w_ctx  = (const float*)d_in[5];
    const float* W_fuse = (const float*)d_in[6];
    const float* bfuse  = (const float*)d_in[7];
    const float* bias   = (const float*)d_in[8];
    const int* idxp     = (const int*)d_in[9];
    const int* idxc     = (const int*)d_in[10];
    float* out0 = (float*)d_out;
    float* out1 = out0 + (size_t)NN * 256;

    char* ws = (char*)d_ws;
    __bf16* Mt = (__bf16*)ws;                              // 256*768*2 = 393216 B
    unsigned char* fp = (unsigned char*)(ws + 393216);     // NN bytes
    unsigned char* fc = fp + NN;                           // NN bytes

    k_setup<<<176, 256, 0, stream>>>(w_orig, w_prop, w_ctx, W_fuse, Mt, fp);
    k_setflags<<<NCC / 256, 256, 0, stream>>>(idxp, idxc, fp, fc);
    k_main<<<2048, 256, 0, stream>>>(hp, hc, horig, Mt, bfuse, bias,
                                     idxp, idxc, fp, fc, out0, out1);
}

// Round 9
// 335.330 us; speedup vs baseline: 1.1843x; 1.1843x over previous
//
#include <hip/hip_runtime.h>
#include <hip/hip_bf16.h>
#include <math.h>

#define NN 262144
#define NCC 65536

typedef __bf16 bf16x8 __attribute__((ext_vector_type(8)));
typedef __bf16 bf16x4 __attribute__((ext_vector_type(4)));
typedef float f32x4 __attribute__((ext_vector_type(4)));

// ---------- setup: blocks 0..47 precompute Mt; blocks 48..175 zero flags ----------
__global__ __launch_bounds__(256) void k_setup(const float* __restrict__ w_orig,
                                               const float* __restrict__ w_prop,
                                               const float* __restrict__ w_ctx,
                                               const float* __restrict__ W_fuse,
                                               __bf16* __restrict__ Mt,
                                               unsigned char* __restrict__ flags) {
    __shared__ float Wl[64 * 65];
    __shared__ float wl[64 * 65];
    int b = blockIdx.x;
    int t = threadIdx.x;
    if (b >= 48) {   // zero 2*NN flag bytes: 128 blocks * 256 threads * 16B
        ((uint4*)flags)[(b - 48) * 256 + t] = make_uint4(0u, 0u, 0u, 0u);
        return;
    }
    int seg = b >> 4, rem = b & 15;
    int ot = rem >> 2, mt = rem & 3;
    const float* wseg = seg == 0 ? w_orig : (seg == 1 ? w_prop : w_ctx);
    int to = (t & 15) * 4, tm = (t >> 4) * 4;
    float acc[4][4] = {};
    for (int kc = 0; kc < 4; ++kc) {
        __syncthreads();
        for (int i = 0; i < 16; ++i) {
            int f = i * 256 + t;
            int row = f >> 6, col = f & 63;
            Wl[row * 65 + col] = W_fuse[(size_t)(ot * 64 + row) * 768 + seg * 256 + kc * 64 + col];
            wl[row * 65 + col] = wseg[(size_t)(mt * 64 + row) * 256 + kc * 64 + col];
        }
        __syncthreads();
        for (int k = 0; k < 64; ++k) {
            float wo[4], wm2[4];
#pragma unroll
            for (int i = 0; i < 4; ++i) wo[i] = Wl[(to + i) * 65 + k];
#pragma unroll
            for (int j = 0; j < 4; ++j) wm2[j] = wl[(tm + j) * 65 + k];
#pragma unroll
            for (int i = 0; i < 4; ++i)
#pragma unroll
                for (int j = 0; j < 4; ++j) acc[i][j] += wo[i] * wm2[j];
        }
    }
    for (int i = 0; i < 4; ++i)
        for (int j = 0; j < 4; ++j) {
            int o = ot * 64 + to + i;
            int g = seg * 256 + mt * 64 + tm + j;
            Mt[(size_t)o * 768 + g] = (__bf16)acc[i][j];
        }
}

__global__ void k_setflags(const int* __restrict__ idxp, const int* __restrict__ idxc,
                           unsigned char* fp, unsigned char* fc) {
    int j = blockIdx.x * blockDim.x + threadIdx.x;
    if (j < NCC) { fp[idxp[j]] = 1; fc[idxc[j]] = 1; }
}

#define MFMA __builtin_amdgcn_mfma_f32_16x16x32_bf16

// ---------- one kernel, two block roles (bit 3): copy 256-row slab / gemm 32x256 tile ----------
__global__ __launch_bounds__(256, 4) void k_main(const float* __restrict__ hp,
                                                 const float* __restrict__ hc,
                                                 const float* __restrict__ horig,
                                                 const __bf16* __restrict__ Mt,
                                                 const float* __restrict__ bfuse,
                                                 const float* __restrict__ bias,
                                                 const int* __restrict__ idxp,
                                                 const int* __restrict__ idxc,
                                                 const unsigned char* __restrict__ fp,
                                                 const unsigned char* __restrict__ fc,
                                                 float* __restrict__ out0,
                                                 float* __restrict__ out1) {
    __shared__ __align__(16) char smem[16384];
    int g = blockIdx.x;
    int role = (g >> 3) & 1;                   // groups of 8 blocks alternate roles (spreads roles over XCDs)
    int bid = ((g >> 4) << 3) | (g & 7);       // 0..2047 within each role
    int t = threadIdx.x;

    if (role == 0) {
        // ================= copy role: 256 rows of one table =================
        int tbl = bid >= 1024;
        int r0 = (tbl ? bid - 1024 : bid) << 8;
        const unsigned char* F = tbl ? fc : fp;
        const float* S = tbl ? hc : hp;
        float* D = tbl ? out1 : out0;
#pragma unroll
        for (int gg = 0; gg < 8; ++gg) {
            unsigned char fl[8];
            f32x4 v[8];
#pragma unroll
            for (int i = 0; i < 8; ++i) {
                int item = (gg * 8 + i) * 256 + t;
                fl[i] = F[r0 + (item >> 6)];
            }
#pragma unroll
            for (int i = 0; i < 8; ++i) {
                int item = (gg * 8 + i) * 256 + t;
                int r = r0 + (item >> 6), slot = item & 63;
                // flagged rows redirect read to slab-first row (cache-hot) -> loads unconditional
                v[i] = *(const f32x4*)(S + (size_t)(fl[i] ? r0 : r) * 256 + slot * 4);
            }
#pragma unroll
            for (int i = 0; i < 8; ++i) {
                int item = (gg * 8 + i) * 256 + t;
                int r = r0 + (item >> 6), slot = item & 63;
                if (!fl[i]) __builtin_nontemporal_store(v[i], (f32x4*)(D + (size_t)r * 256 + slot * 4));
            }
        }
        return;
    }

    // ================= gemm role: 32x256 output tile, 4 waves =================
    int jbase = bid * 32;
    int lane = t & 63, wid = t >> 6;
    int l15 = lane & 15, lq = lane >> 4;

    // B fragment base pointers: wave wid owns cols [wid*64, wid*64+64)
    const __bf16* bp[4];
#pragma unroll
    for (int ni = 0; ni < 4; ++ni)
        bp[ni] = Mt + (size_t)(wid * 64 + ni * 16 + l15) * 768 + lq * 8;

    f32x4 acc[2][4] = {};

#pragma unroll
    for (int seg = 0; seg < 3; ++seg) {
        __syncthreads();   // previous seg's LDS reads complete
        // ---- stage 32 rows x 256 k: wave wid stages rows wid*8..wid*8+7, 1KB burst per row ----
#pragma unroll
        for (int b2 = 0; b2 < 2; ++b2) {
            f32x4 v[4];
#pragma unroll
            for (int i = 0; i < 4; ++i) {
                int r = wid * 8 + b2 * 4 + i;
                int j = jbase + r;
                const float* src = seg == 0 ? horig + (size_t)j * 256
                                 : seg == 1 ? hp + (size_t)idxp[j] * 256
                                            : hc + (size_t)idxc[j] * 256;
                v[i] = *(const f32x4*)(src + lane * 4);
            }
#pragma unroll
            for (int i = 0; i < 4; ++i) {
                int r = wid * 8 + b2 * 4 + i;
                bf16x4 w;
                w[0] = (__bf16)v[i][0]; w[1] = (__bf16)v[i][1];
                w[2] = (__bf16)v[i][2]; w[3] = (__bf16)v[i][3];
                // lane covers k = lane*4..lane*4+4 -> chunk lq, slot (l15)>>1, half l15&1
                int off = lq * 4096 + r * 128 + ((((l15) >> 1) ^ (r & 7)) << 4) + (l15 & 1) * 8;
                *(bf16x4*)(smem + off) = w;
            }
        }
        __syncthreads();
        // ---- compute 4 chunks of this seg ----
#pragma unroll
        for (int c = 0; c < 4; ++c) {
            int cg = seg * 4 + c;
            bf16x8 bfr[4][2];
#pragma unroll
            for (int ni = 0; ni < 4; ++ni)
#pragma unroll
                for (int ks = 0; ks < 2; ++ks)
                    bfr[ni][ks] = *(const bf16x8*)(bp[ni] + cg * 64 + ks * 32);
            bf16x8 af[2][2];
#pragma unroll
            for (int mi = 0; mi < 2; ++mi)
#pragma unroll
                for (int ks = 0; ks < 2; ++ks) {
                    int row = mi * 16 + l15;
                    int sl = ks * 4 + lq;
                    af[mi][ks] = *(const bf16x8*)(smem + c * 4096 + row * 128 + ((sl ^ (row & 7)) << 4));
                }
#pragma unroll
            for (int ks = 0; ks < 2; ++ks)
#pragma unroll
                for (int mi = 0; mi < 2; ++mi)
#pragma unroll
                    for (int ni = 0; ni < 4; ++ni)
                        acc[mi][ni] = MFMA(af[mi][ks], bfr[ni][ks], acc[mi][ni], 0, 0, 0);
        }
    }

    // ---- epilogue: per-wave LDS transpose -> f32x4 contiguous scattered stores ----
    float bfv[4], biv[4];
#pragma unroll
    for (int ni = 0; ni < 4; ++ni) {
        int o = wid * 64 + ni * 16 + l15;
        bfv[ni] = bfuse[o];
        biv[ni] = bias[o];
    }
    __syncthreads();   // all LDS reads done; reuse smem as scratch
    float* scr = (float*)(smem + wid * 4096);   // per-wave 16x64 f32
#pragma unroll
    for (int mi = 0; mi < 2; ++mi) {
#pragma unroll
        for (int ni = 0; ni < 4; ++ni)
#pragma unroll
            for (int rr = 0; rr < 4; ++rr) {
                float v = tanhf(acc[mi][ni][rr] + bfv[ni]) + biv[ni];
                scr[(lq * 4 + rr) * 64 + ni * 16 + l15] = v;
            }
        // intra-wave ds ordering makes our own writes visible to our own reads
#pragma unroll
        for (int rnd = 0; rnd < 4; ++rnd) {
            int rr2 = rnd * 4 + lq;
            int j = jbase + mi * 16 + rr2;
            int gp = idxp[j], gc = idxc[j];
            f32x4 v = *(const f32x4*)&scr[rr2 * 64 + l15 * 4];
            *(f32x4*)(out0 + (size_t)gp * 256 + wid * 64 + l15 * 4) = v;
            *(f32x4*)(out1 + (size_t)gc * 256 + wid * 64 + l15 * 4) = v;
        }
    }
}

extern "C" void kernel_launch(void* const* d_in, const int* in_sizes, int n_in,
                              void* d_out, int out_size, void* d_ws, size_t ws_size,
                              hipStream_t stream) {
    const float* hp     = (const float*)d_in[0];
    const float* hc     = (const float*)d_in[1];
    const float* horig  = (const float*)d_in[2];
    const float* w_orig = (const float*)d_in[3];
    const float* w_prop = (const float*)d_in[4];
    const float* w_ctx  = (const float*)d_in[5];
    const float* W_fuse = (const float*)d_in[6];
    const float* bfuse  = (const float*)d_in[7];
    const float* bias   = (const float*)d_in[8];
    const int* idxp     = (const int*)d_in[9];
    const int* idxc     = (const int*)d_in[10];
    float* out0 = (float*)d_out;
    float* out1 = out0 + (size_t)NN * 256;

    char* ws = (char*)d_ws;
    __bf16* Mt = (__bf16*)ws;                              // 256*768*2 = 393216 B
    unsigned char* fp = (unsigned char*)(ws + 393216);     // NN bytes
    unsigned char* fc = fp + NN;                           // NN bytes

    k_setup<<<176, 256, 0, stream>>>(w_orig, w_prop, w_ctx, W_fuse, Mt, fp);
    k_setflags<<<NCC / 256, 256, 0, stream>>>(idxp, idxc, fp, fc);
    k_main<<<4096, 256, 0, stream>>>(hp, hc, horig, Mt, bfuse, bias,
                                     idxp, idxc, fp, fc, out0, out1);
}